// Round 5
// baseline (279.011 us; speedup 1.0000x reference)
//
#include <hip/hip_runtime.h>

// out[i]        = p[i]                      i in [0, SIZE)
// out[SIZE + i] = w[i] * selu(p[i]) + q[i]
//
// Round-6 (resubmit after container failure in round-4; never measured):
// persistent grid-stride shape (Guideline 11), single dispatch,
// traffic-weighted block-role split.
// Evidence trail:
//  - r4/r5 counters: 2.6-2.8 TB/s HBM (32-35%), VALUBusy 4%, occupancy 61%
//  - r5 unroll x4 was confounded (VGPR=32 -> compiler re-rolled) AND the
//    in-flight math (~60 KB/CU outstanding >> ~9 KB needed) rules out
//    latency/MLP as the limiter.
//  - every fast memory kernel measured on this chip (fill: 6.8 TB/s at
//    9.6% occupancy; m13 copy probe: 6.3 TB/s) is the persistent
//    grid-stride shape with ~2k blocks; ours was 8k-32k one-shot blocks.
// Role weighting: copy moves 32 B/float4, selu 64 B/float4 -> 1:2 block
// split (bid%3==0 copy, else selu) so both roles retire together.

typedef float v4f __attribute__((ext_vector_type(4)));

__global__ void __launch_bounds__(256)
persistent_roles(const v4f* __restrict__ x4, const v4f* __restrict__ w4,
                 v4f* __restrict__ out4, int n4) {
    const int bid   = blockIdx.x;
    const int ncopy = (gridDim.x + 2) / 3;            // 683 of 2048
    const bool is_copy = (bid % 3) == 0;

    if (is_copy) {
        // out[0:SIZE) = p   (2 streams, grid-stride)
        const int rank   = bid / 3;
        const int stride = ncopy * 256;
        for (int i = rank * 256 + (int)threadIdx.x; i < n4; i += stride)
            out4[i] = x4[i];
    } else {
        // out[SIZE:N) = w * selu(p) + q   (4 streams, grid-stride)
        const int nselu  = (int)gridDim.x - ncopy;    // 1365
        const int rank   = bid - (bid + 2) / 3;       // dense rank among selu blocks
        const int stride = nselu * 256;
        const float scale = 1.0507009873554805f;
        const float alpha = 1.6732632423543773f;

        for (int i = rank * 256 + (int)threadIdx.x; i < n4; i += stride) {
            v4f p = x4[i];
            v4f q = x4[n4 + i];
            v4f w = w4[i];
            v4f r;
#pragma unroll
            for (int c = 0; c < 4; ++c) {
                float pv = p[c];
                float s  = pv > 0.f ? pv : alpha * (__expf(pv) - 1.f);
                r[c] = w[c] * (scale * s) + q[c];
            }
            out4[n4 + i] = r;
        }
    }
}

extern "C" void kernel_launch(void* const* d_in, const int* in_sizes, int n_in,
                              void* d_out, int out_size, void* d_ws, size_t ws_size,
                              hipStream_t stream) {
    const v4f* x4 = (const v4f*)d_in[0];
    const v4f* w4 = (const v4f*)d_in[1];
    v4f* out4 = (v4f*)d_out;

    int size = in_sizes[1];      // SIZE = N/2 = 16777216
    int n4 = size / 4;           // 4194304 float4 per half

    int block = 256;
    int grid  = 2048;            // 8 blocks/CU, persistent grid-stride

    persistent_roles<<<grid, block, 0, stream>>>(x4, w4, out4, n4);
}